// Round 12
// baseline (343.311 us; speedup 1.0000x reference)
//
#include <hip/hip_runtime.h>

typedef __attribute__((ext_vector_type(8))) short short8;
typedef __attribute__((ext_vector_type(4))) float f32x4;
typedef unsigned short u16;

#define NTOK 49
#define NBLK 4096
#define LOG2E 1.4426950408889634f

// LDS pool (u16 units), 64 KB -> 2 blocks/CU
#define XF 0        // x frags [rt4][ks8][64][8] linear; later y frags [it4][h8][64][8]
#define VY 16384    // 32 slots x 512 u16: v^T frag f(=dblk*2+k2) of head h at slot f*8+h
#define POOLN 32768

// workspace byte offsets
#define WS_WQT 0          // u16 wqTf[48][8][64][8]    = 393216
#define WS_WOT 393216     // u16 woTf[16][8][64][8]    = 131072
#define WS_BIAS 524288    // float biasf[8][16][64][4] = 131072   (x LOG2E)
#define WS_MKG 655360     // float mkg[64][16][64][4]  = 1048576  (x LOG2E)

__device__ __forceinline__ u16 f2bf(float f) {
  unsigned u = __float_as_uint(f);
  return (u16)((u + 0x7fffu + ((u >> 16) & 1u)) >> 16);
}
// single-instruction packed f32x2 -> bf16x2 (RNE)
__device__ __forceinline__ unsigned packbf(float a, float b) {
  unsigned r;
  asm("v_cvt_pk_bf16_f32 %0, %1, %2" : "=v"(r) : "v"(a), "v"(b));
  return r;
}

// Cross-lane fragment assembly (R7/R8-verified).
__device__ __forceinline__ short8 asm_frag(unsigned c0p0, unsigned c0p1,
                                           unsigned c1p0, unsigned c1p1,
                                           int srcA, int srcB, bool cSel) {
  unsigned a0 = (unsigned)__shfl((int)c0p0, srcA);
  unsigned b0 = (unsigned)__shfl((int)c1p0, srcA);
  unsigned a1 = (unsigned)__shfl((int)c0p1, srcA);
  unsigned b1 = (unsigned)__shfl((int)c1p1, srcA);
  unsigned a2 = (unsigned)__shfl((int)c0p0, srcB);
  unsigned b2 = (unsigned)__shfl((int)c1p0, srcB);
  unsigned a3 = (unsigned)__shfl((int)c0p1, srcB);
  unsigned b3 = (unsigned)__shfl((int)c1p1, srcB);
  union { unsigned u[4]; short8 s8; } r;
  r.u[0] = cSel ? b0 : a0;
  r.u[1] = cSel ? b1 : a1;
  r.u[2] = cSel ? b2 : a2;
  r.u[3] = cSel ? b3 : a3;
  return r.s8;
}

// ---------------- prep: frag-order weights (bf16), scaled bias + mask tables ----------------
__global__ void prep_kernel(const float* __restrict__ w_qkv,
                            const float* __restrict__ w_out,
                            const float* __restrict__ rel,
                            const float* __restrict__ mask,
                            u16* __restrict__ wqTf,
                            u16* __restrict__ woTf,
                            float* __restrict__ biasf,
                            float* __restrict__ mkg) {
  const int stride = gridDim.x * blockDim.x;
  const int gid = blockIdx.x * blockDim.x + threadIdx.x;
  for (int e = gid; e < 48 * 8 * 64 * 8; e += stride) {
    int eL = e & 7, ln = (e >> 3) & 63, ks = (e >> 9) & 7, ctg = e >> 12;
    int k = ks * 32 + (ln >> 4) * 8 + eL;
    int c = ctg * 16 + (ln & 15);
    wqTf[e] = f2bf(w_qkv[k * 768 + c]);
  }
  for (int e = gid; e < 16 * 8 * 64 * 8; e += stride) {
    int eL = e & 7, ln = (e >> 3) & 63, ks = (e >> 9) & 7, ctg = e >> 12;
    int k = ks * 32 + (ln >> 4) * 8 + eL;
    int c = ctg * 16 + (ln & 15);
    woTf[e] = f2bf(w_out[k * 256 + c]);
  }
  for (int e = gid; e < 8 * 16 * 64 * 4; e += stride) {
    int rg = e & 3, ln = (e >> 2) & 63, t = (e >> 8) & 15, hh = e >> 12;
    int i = (t >> 2) * 16 + (ln & 15);
    int j = (t & 3) * 16 + (ln >> 4) * 4 + rg;
    float v;
    if (j >= NTOK) v = -1e30f;
    else if (i >= NTOK) v = 0.f;
    else {
      int dh = i / 7 - j / 7 + 6;
      int dw = i % 7 - j % 7 + 6;
      v = rel[(dh * 13 + dw) * 8 + hh];
    }
    biasf[e] = v * LOG2E;
  }
  for (int e = gid; e < 64 * 16 * 64 * 4; e += stride) {
    int rg = e & 3, ln = (e >> 2) & 63, t = (e >> 8) & 15, wdw = e >> 12;
    int i = (t >> 2) * 16 + (ln & 15);
    int j = (t & 3) * 16 + (ln >> 4) * 4 + rg;
    mkg[e] = (i < NTOK && j < NTOK) ? mask[wdw * (NTOK * NTOK) + i * NTOK + j] * LOG2E : 0.f;
  }
}

// ---------------- fused window attention: 8 waves, wave = head, 2 blocks/CU ----------------
__global__ void __launch_bounds__(512, 2) winattn_mfma(
    const float* __restrict__ x,
    const float* __restrict__ b_qkv,
    const float* __restrict__ b_out,
    const u16* __restrict__ wqTf,
    const u16* __restrict__ woTf,
    const float* __restrict__ biasf,
    const float* __restrict__ mkg,
    float* __restrict__ out)
{
  __shared__ u16 pool[POOLN];
  const int b = blockIdx.x, tid = threadIdx.x;
  const int lane = tid & 63, lo = lane & 15, hi = lane >> 4;
  const int h = tid >> 6;                    // wave = head, 0..7
  const f32x4 zf = {0.f, 0.f, 0.f, 0.f};

  // ---- stage: x -> linear frag order ----
  {
    const float4* xg = (const float4*)(x + (size_t)b * (NTOK * 256));
    for (int e = tid; e < 49 * 64; e += 512) {
      float4 v = xg[e];
      int r = e >> 6, c4 = (e & 63) << 2;
      int addr = (((r >> 4) * 8 + (c4 >> 5)) * 64 + ((c4 >> 3) & 3) * 16 + (r & 15)) * 8 + (c4 & 7);
      *(uint2*)&pool[XF + addr] = make_uint2(packbf(v.x, v.y), packbf(v.z, v.w));
    }
    if (tid < 15 * 64) {   // zero-pad tokens 49..63
      int e = tid;
      int r = 49 + (e >> 6), c4 = (e & 63) << 2;
      int addr = (((r >> 4) * 8 + (c4 >> 5)) * 64 + ((c4 >> 3) & 3) * 16 + (r & 15)) * 8 + (c4 & 7);
      *(uint2*)&pool[XF + addr] = make_uint2(0u, 0u);
    }
  }
  __syncthreads();   // (a) xf ready

  const int srcA = lo + 32 * (hi & 1);
  const int srcB = srcA + 16;
  const bool cSel = (hi & 2) != 0;

  // ---- phase 1: QKV GEMM for head h — 3 passes of 2 ctgs (acc peak 32) ----
  short8 qa[4], ka[4];
  {
    unsigned pq[2][4][2];
    // pass 0: q ctgs {2h, 2h+1}
    {
      f32x4 acc[2][4];
      #pragma unroll
      for (int ct = 0; ct < 2; ++ct)
        #pragma unroll
        for (int rt = 0; rt < 4; ++rt) acc[ct][rt] = zf;
      #pragma unroll
      for (int ks = 0; ks < 8; ++ks) {
        short8 bx[4];
        #pragma unroll
        for (int rt = 0; rt < 4; ++rt)
          bx[rt] = *(const short8*)&pool[XF + ((rt * 8 + ks) * 64 + lane) * 8];
        short8 af0 = *(const short8*)&wqTf[((size_t)((2 * h) * 8 + ks) * 64 + lane) * 8];
        short8 af1 = *(const short8*)&wqTf[((size_t)((2 * h + 1) * 8 + ks) * 64 + lane) * 8];
        #pragma unroll
        for (int rt = 0; rt < 4; ++rt) {
          acc[0][rt] = __builtin_amdgcn_mfma_f32_16x16x32_bf16(af0, bx[rt], acc[0][rt], 0, 0, 0);
          acc[1][rt] = __builtin_amdgcn_mfma_f32_16x16x32_bf16(af1, bx[rt], acc[1][rt], 0, 0, 0);
        }
      }
      #pragma unroll
      for (int ct = 0; ct < 2; ++ct) {
        f32x4 bias = *(const f32x4*)(b_qkv + (2 * h + ct) * 16 + hi * 4);
        #pragma unroll
        for (int rt = 0; rt < 4; ++rt) {
          f32x4 v = acc[ct][rt] + bias;
          pq[ct][rt][0] = packbf(v[0], v[1]);
          pq[ct][rt][1] = packbf(v[2], v[3]);
        }
      }
    }
    // pass 1: k ctgs {16+2h, 17+2h} -> ka
    {
      f32x4 acc[2][4];
      #pragma unroll
      for (int ct = 0; ct < 2; ++ct)
        #pragma unroll
        for (int rt = 0; rt < 4; ++rt) acc[ct][rt] = zf;
      #pragma unroll
      for (int ks = 0; ks < 8; ++ks) {
        short8 bx[4];
        #pragma unroll
        for (int rt = 0; rt < 4; ++rt)
          bx[rt] = *(const short8*)&pool[XF + ((rt * 8 + ks) * 64 + lane) * 8];
        short8 af0 = *(const short8*)&wqTf[((size_t)((16 + 2 * h) * 8 + ks) * 64 + lane) * 8];
        short8 af1 = *(const short8*)&wqTf[((size_t)((17 + 2 * h) * 8 + ks) * 64 + lane) * 8];
        #pragma unroll
        for (int rt = 0; rt < 4; ++rt) {
          acc[0][rt] = __builtin_amdgcn_mfma_f32_16x16x32_bf16(af0, bx[rt], acc[0][rt], 0, 0, 0);
          acc[1][rt] = __builtin_amdgcn_mfma_f32_16x16x32_bf16(af1, bx[rt], acc[1][rt], 0, 0, 0);
        }
      }
      unsigned pk[2][4][2];
      #pragma unroll
      for (int ct = 0; ct < 2; ++ct) {
        f32x4 bias = *(const f32x4*)(b_qkv + (16 + 2 * h + ct) * 16 + hi * 4);
        #pragma unroll
        for (int rt = 0; rt < 4; ++rt) {
          f32x4 v = acc[ct][rt] + bias;
          pk[ct][rt][0] = packbf(v[0], v[1]);
          pk[ct][rt][1] = packbf(v[2], v[3]);
        }
      }
      #pragma unroll
      for (int it = 0; it < 4; ++it)
        ka[it] = asm_frag(pk[0][it][0], pk[0][it][1], pk[1][it][0], pk[1][it][1],
                          srcA, srcB, cSel);
    }
    // pass 2: v ctgs {32+2h, 33+2h}, swapped-operand (R10/R11-verified) -> LDS v^T
    {
      f32x4 acc[2][4];
      #pragma unroll
      for (int ct = 0; ct < 2; ++ct)
        #pragma unroll
        for (int rt = 0; rt < 4; ++rt) acc[ct][rt] = zf;
      #pragma unroll
      for (int ks = 0; ks < 8; ++ks) {
        short8 bx[4];
        #pragma unroll
        for (int rt = 0; rt < 4; ++rt)
          bx[rt] = *(const short8*)&pool[XF + ((rt * 8 + ks) * 64 + lane) * 8];
        short8 af0 = *(const short8*)&wqTf[((size_t)((32 + 2 * h) * 8 + ks) * 64 + lane) * 8];
        short8 af1 = *(const short8*)&wqTf[((size_t)((33 + 2 * h) * 8 + ks) * 64 + lane) * 8];
        #pragma unroll
        for (int rt = 0; rt < 4; ++rt) {
          acc[0][rt] = __builtin_amdgcn_mfma_f32_16x16x32_bf16(bx[rt], af0, acc[0][rt], 0, 0, 0);
          acc[1][rt] = __builtin_amdgcn_mfma_f32_16x16x32_bf16(bx[rt], af1, acc[1][rt], 0, 0, 0);
        }
      }
      #pragma unroll
      for (int ct = 0; ct < 2; ++ct) {
        const float bv = b_qkv[(32 + 2 * h + ct) * 16 + lo];
        #pragma unroll
        for (int rt = 0; rt < 4; ++rt) {
          f32x4 v = acc[ct][rt];
          float v0 = v[0] + bv, v1 = v[1] + bv, v2 = v[2] + bv, v3 = v[3] + bv;
          int f = ct * 2 + (rt >> 1);
          int hiR = (rt & 1) * 2 + (hi >> 1);
          int eb = (hi & 1) * 4;
          *(uint2*)&pool[VY + (f * 8 + h) * 512 + (hiR * 16 + lo) * 8 + eb] =
              make_uint2(packbf(v0, v1), packbf(v2, v3));
        }
      }
    }
    // q -> A-frags (pq dies here)
    #pragma unroll
    for (int jt = 0; jt < 4; ++jt)
      qa[jt] = asm_frag(pq[0][jt][0], pq[0][jt][1], pq[1][jt][0], pq[1][jt][1],
                        srcA, srcB, cSel);
  }
  __syncthreads();   // (b) all XF(x) reads done -> y may overwrite

  // ---- phases 2-4 fused per i-tile: QK^T -> softmax -> PV (all wave-local) ----
  {
    short8 va[2][2];
    #pragma unroll
    for (int dblk = 0; dblk < 2; ++dblk)
      #pragma unroll
      for (int k2 = 0; k2 < 2; ++k2)
        va[dblk][k2] = *(const short8*)&pool[VY + ((dblk * 2 + k2) * 8 + h) * 512 + lane * 8];
    const float SC = 0.17677669529663687f * LOG2E;
    const float* bh = biasf + h * 4096;
    const float* mh = mkg + (size_t)(b & 63) * 4096;
    #pragma unroll
    for (int it = 0; it < 4; ++it) {
      float rs = 0.f;
      unsigned pit[4][2];
      #pragma unroll
      for (int jt = 0; jt < 4; ++jt) {
        f32x4 s = __builtin_amdgcn_mfma_f32_16x16x32_bf16(qa[jt], ka[it], zf, 0, 0, 0);
        const int t = it * 4 + jt;
        f32x4 bm = *(const f32x4*)&bh[(t * 64 + lane) * 4];
        f32x4 mm = *(const f32x4*)&mh[(t * 64 + lane) * 4];
        float p0 = exp2f(fmaf(s[0], SC, bm[0] + mm[0]));
        float p1 = exp2f(fmaf(s[1], SC, bm[1] + mm[1]));
        float p2 = exp2f(fmaf(s[2], SC, bm[2] + mm[2]));
        float p3 = exp2f(fmaf(s[3], SC, bm[3] + mm[3]));
        rs += (p0 + p1) + (p2 + p3);
        pit[jt][0] = packbf(p0, p1);
        pit[jt][1] = packbf(p2, p3);
      }
      float r2 = rs + __shfl_xor(rs, 16);
      const float inv = 1.f / (r2 + __shfl_xor(r2, 32));
      f32x4 ya0 = zf, ya1 = zf;
      #pragma unroll
      for (int k2 = 0; k2 < 2; ++k2) {
        short8 pb = asm_frag(pit[2 * k2][0], pit[2 * k2][1],
                             pit[2 * k2 + 1][0], pit[2 * k2 + 1][1], srcA, srcB, cSel);
        ya0 = __builtin_amdgcn_mfma_f32_16x16x32_bf16(va[0][k2], pb, ya0, 0, 0, 0);
        ya1 = __builtin_amdgcn_mfma_f32_16x16x32_bf16(va[1][k2], pb, ya1, 0, 0, 0);
      }
      #pragma unroll
      for (int dblk = 0; dblk < 2; ++dblk) {
        f32x4 yy = dblk ? ya1 : ya0;
        int hi2 = dblk * 2 + (hi >> 1);
        int eb = (hi & 1) * 4;
        *(uint2*)&pool[XF + ((it * 8 + h) * 64 + hi2 * 16 + lo) * 8 + eb] =
            make_uint2(packbf(yy[0] * inv, yy[1] * inv), packbf(yy[2] * inv, yy[3] * inv));
      }
    }
  }
  __syncthreads();   // (c) all y frags visible

  // ---- phase 5: output projection, 2 ctgs per wave ----
  {
    f32x4 pacc[2][4];
    #pragma unroll
    for (int ct = 0; ct < 2; ++ct)
      #pragma unroll
      for (int rt = 0; rt < 4; ++rt) pacc[ct][rt] = zf;
    #pragma unroll
    for (int ks = 0; ks < 8; ++ks) {
      short8 yb[4];
      #pragma unroll
      for (int rt = 0; rt < 4; ++rt)
        yb[rt] = *(const short8*)&pool[XF + ((rt * 8 + ks) * 64 + lane) * 8];
      #pragma unroll
      for (int ct = 0; ct < 2; ++ct) {
        short8 wf = *(const short8*)&woTf[((size_t)((h * 2 + ct) * 8 + ks) * 64 + lane) * 8];
        #pragma unroll
        for (int rt = 0; rt < 4; ++rt)
          pacc[ct][rt] = __builtin_amdgcn_mfma_f32_16x16x32_bf16(wf, yb[rt], pacc[ct][rt], 0, 0, 0);
      }
    }
    float* og = out + (size_t)b * (NTOK * 256);
    #pragma unroll
    for (int ct = 0; ct < 2; ++ct) {
      const int cb = (h * 2 + ct) * 16 + hi * 4;
      f32x4 bb = *(const f32x4*)(b_out + cb);
      #pragma unroll
      for (int rt = 0; rt < 4; ++rt) {
        const int r = rt * 16 + lo;
        if (r < NTOK) {
          f32x4 vv = pacc[ct][rt] + bb;
          *(f32x4*)(og + (size_t)r * 256 + cb) = vv;
        }
      }
    }
  }
}

extern "C" void kernel_launch(void* const* d_in, const int* in_sizes, int n_in,
                              void* d_out, int out_size, void* d_ws, size_t ws_size,
                              hipStream_t stream) {
  const float *x = nullptr, *mask = nullptr, *w_qkv = nullptr, *b_qkv = nullptr,
              *rel_t = nullptr, *w_out = nullptr, *b_out = nullptr;
  for (int i = 0; i < n_in; ++i) {
    const float* p = (const float*)d_in[i];
    switch (in_sizes[i]) {
      case 4096 * 49 * 256: x = p; break;
      case 64 * 49 * 49:    mask = p; break;
      case 256 * 768:       w_qkv = p; break;
      case 768:             b_qkv = p; break;
      case 169 * 8:         rel_t = p; break;
      case 256 * 256:       w_out = p; break;
      case 256:             b_out = p; break;
    }
  }
  char* wsb = (char*)d_ws;
  u16* wqTf    = (u16*)(wsb + WS_WQT);
  u16* woTf    = (u16*)(wsb + WS_WOT);
  float* biasf = (float*)(wsb + WS_BIAS);
  float* mkg   = (float*)(wsb + WS_MKG);

  hipLaunchKernelGGL(prep_kernel, dim3(1024), dim3(256), 0, stream,
                     w_qkv, w_out, rel_t, mask, wqTf, woTf, biasf, mkg);
  hipLaunchKernelGGL(winattn_mfma, dim3(NBLK), dim3(512), 0, stream,
                     x, b_qkv, b_out, wqTf, woTf, biasf, mkg, (float*)d_out);
}